// Round 7
// baseline (1865.666 us; speedup 1.0000x reference)
//
#include <hip/hip_runtime.h>
#include <math.h>

#define NPTS 4096
#define MC   1024
#define KNB  32

typedef __attribute__((ext_vector_type(8))) short bf16x8;
typedef __attribute__((ext_vector_type(4))) float f32x4;
typedef __attribute__((ext_vector_type(2))) float f32x2;

__device__ __forceinline__ unsigned short f2bf(float f) {
  unsigned int u = __float_as_uint(f);
  u = u + 0x7fffu + ((u >> 16) & 1u);   // round-to-nearest-even
  return (unsigned short)(u >> 16);
}

template <int CTRL>
__device__ __forceinline__ float dpp_max(float v) {
  int o = __builtin_amdgcn_update_dpp(__float_as_int(v), __float_as_int(v), CTRL, 0xF, 0xF, false);
  return fmaxf(v, __int_as_float(o));
}

// ---------------------------------------------------------------------------
// Kernel 1 (fused): blocks 0..7 = FPS (batch PAIR per block), 8..519 =
// feature transpose, 520..524 = weight pack.
//
// FPS R7: R6 (670us WIN, VGPR=88 resident) proved the packed-f32x2
// formulation is the one this allocator keeps resident. Exploit it to pair
// batches: element 0 = batch A, element 1 = batch B of the SAME f32x2 state
// arrays (identical register footprint to R6), so ONE iteration advances
// TWO independent FPS chains and the ~1330cyc reduce+sync phase is paid
// once per pair. 512 thr x 8 pts/lane/batch, idx = k*2048+4t+c (R5-verified
// mapping; R5 was correct, only spilled -- its scalar dual-array state is
// exactly what the packing removes). Update = R6's packed loop with
// Lx={lxA,lxB} (broadcasts pack too). Reduce A then reduce B SEQUENTIALLY
// (one scan context live at a time -> minimal pressure), each the
// R6-proven DPP+readlane+8ballot+SALU-scan. ONE barrier, two 8-key
// tournaments. A-coords fetched from LDS (48KB staged); B winner coords
// from global via readfirstlane scalar loads (R5-proven; L2-resident).
// Centroids stream straight to out_cent at loop top (~1000cyc slack before
// the barrier's vmcnt drain -> free), deleting slog + epilogue copy.
// Exact jnp.argmax semantics: scan k asc -> ctz lane -> lowest c == lowest
// global index; cross-wave u64 key (dist<<32 | ~idx) max; dist math
// bit-exact (contract off, elementwise IEEE rn).
// Ledger (do NOT revisit): R1 8-wave lockstep on SINGLE batch (+138us),
// R2 volatile spin (serialized LDS), R3/R4 mux-payload (spill), R5 scalar
// dual-array pair (spill@44). Fallback if this spills: R6 verbatim (950us).
// ---------------------------------------------------------------------------
struct FpsShared {
  float sxA[NPTS], syA[NPTS], szA[NPTS];
  unsigned long long skey[2][2][8];   // [batch][parity][wave]: dist<<32 | ~idx
};
struct TransShared {
  float tile[64][129];   // stride%32==1 -> conflict-free both phases
};

__global__ __launch_bounds__(512, 1) void fused_pre(
    const float* __restrict__ points, const float* __restrict__ feats,
    const float* __restrict__ w1, const float* __restrict__ w2,
    const float* __restrict__ w3,
    unsigned short* __restrict__ featsT, unsigned short* __restrict__ wpack,
    float* __restrict__ out_cent) {
  __shared__ union { FpsShared f; TransShared tr; } S;
  const int blk = blockIdx.x;
  const int t = threadIdx.x;

  if (blk < 8) {
    // ============== FPS: batches 2*blk (A) and 2*blk+1 (B) ==============
    const int w = t >> 6;
    const float* pA = points + (size_t)(2 * blk) * 3 * NPTS;
    const float* pB = pA + 3 * NPTS;

    // slot p = k*4+c holds point idx = k*2048 + 4t + c of A (elem0), B (elem1)
    f32x2 fx[8], fy[8], fz[8], dist[8];
#pragma unroll
    for (int k = 0; k < 2; ++k) {
      float4 XA = ((const float4*)pA)[k * 512 + t];
      float4 YA = ((const float4*)(pA + NPTS))[k * 512 + t];
      float4 ZA = ((const float4*)(pA + 2 * NPTS))[k * 512 + t];
      ((float4*)S.f.sxA)[k * 512 + t] = XA;
      ((float4*)S.f.syA)[k * 512 + t] = YA;
      ((float4*)S.f.szA)[k * 512 + t] = ZA;
      float4 XB = ((const float4*)pB)[k * 512 + t];
      float4 YB = ((const float4*)(pB + NPTS))[k * 512 + t];
      float4 ZB = ((const float4*)(pB + 2 * NPTS))[k * 512 + t];
      fx[k * 4 + 0] = (f32x2){XA.x, XB.x}; fx[k * 4 + 1] = (f32x2){XA.y, XB.y};
      fx[k * 4 + 2] = (f32x2){XA.z, XB.z}; fx[k * 4 + 3] = (f32x2){XA.w, XB.w};
      fy[k * 4 + 0] = (f32x2){YA.x, YB.x}; fy[k * 4 + 1] = (f32x2){YA.y, YB.y};
      fy[k * 4 + 2] = (f32x2){YA.z, YB.z}; fy[k * 4 + 3] = (f32x2){YA.w, YB.w};
      fz[k * 4 + 0] = (f32x2){ZA.x, ZB.x}; fz[k * 4 + 1] = (f32x2){ZA.y, ZB.y};
      fz[k * 4 + 2] = (f32x2){ZA.z, ZB.z}; fz[k * 4 + 3] = (f32x2){ZA.w, ZB.w};
    }
#pragma unroll
    for (int p = 0; p < 8; ++p) dist[p] = (f32x2){1e10f, 1e10f};
    __syncthreads();

    float lxA = pA[0], lyA = pA[NPTS], lzA = pA[2 * NPTS];
    float lxB = pB[0], lyB = pB[NPTS], lzB = pB[2 * NPTS];
    float* ocA = out_cent + (size_t)(2 * blk) * 3 * MC;
    float* ocB = ocA + 3 * MC;

    for (int i = 0; i < MC; ++i) {
      // stream centroids to global early: ~1000cyc of slack before the
      // barrier's vmcnt drain -> store latency fully hidden
      if (t == 0)   { ocA[i] = lxA; ocA[MC + i] = lyA; ocA[2 * MC + i] = lzA; }
      if (t == 256) { ocB[i] = lxB; ocB[MC + i] = lyB; ocB[2 * MC + i] = lzB; }
      if (i == MC - 1) break;

      // ---- packed dual-batch distance update (bit-exact: contract off) ----
      float mA, mB;
      {
#pragma clang fp contract(off)
        const f32x2 Lx = {lxA, lxB};
        const f32x2 Ly = {lyA, lyB};
        const f32x2 Lz = {lzA, lzB};
        mA = -1.0f; mB = -1.0f;
#pragma unroll
        for (int p = 0; p < 8; ++p) {
          f32x2 dx = fx[p] - Lx;
          f32x2 dy = fy[p] - Ly;
          f32x2 dz = fz[p] - Lz;
          f32x2 d  = dx * dx + dy * dy + dz * dz;   // pk_mul + pk_add, no fma
          float dm0 = fminf(dist[p][0], d[0]);
          float dm1 = fminf(dist[p][1], d[1]);
          dist[p][0] = dm0;
          dist[p][1] = dm1;
          mA = fmaxf(mA, dm0);
          mB = fmaxf(mB, dm1);
        }
      }

      const int par = i & 1;
      // ---- reduce A (sequential: one scan context live at a time) ----
      {
        float m = mA;
        m = dpp_max<0x111>(m); m = dpp_max<0x112>(m); m = dpp_max<0x114>(m);
        m = dpp_max<0x118>(m); m = dpp_max<0x142>(m); m = dpp_max<0x143>(m);
        const float wv = __int_as_float(__builtin_amdgcn_readlane(__float_as_int(m), 63));
        unsigned long long mk[2][4];
#pragma unroll
        for (int k = 0; k < 2; ++k) {
          mk[k][0] = __ballot(dist[k * 4 + 0][0] == wv);
          mk[k][1] = __ballot(dist[k * 4 + 1][0] == wv);
          mk[k][2] = __ballot(dist[k * 4 + 2][0] == wv);
          mk[k][3] = __ballot(dist[k * 4 + 3][0] == wv);
        }
        unsigned long long s0 = 0, s1 = 0, s2 = 0, s3 = 0, anyk = 0;
        int sk = -1;
#pragma unroll
        for (int k = 0; k < 2; ++k) {
          unsigned long long a = mk[k][0] | mk[k][1] | mk[k][2] | mk[k][3];
          if (sk < 0 && a != 0ull) {
            sk = k; anyk = a;
            s0 = mk[k][0]; s1 = mk[k][1]; s2 = mk[k][2]; s3 = mk[k][3];
          }
        }
        const int l = __builtin_ctzll(anyk);
        const unsigned long long bit = 1ull << l;
        const int c = (s0 & bit) ? 0 : (s1 & bit) ? 1 : (s2 & bit) ? 2 : 3;
        const int selIdx = sk * 2048 + 256 * w + 4 * l + c;
        if ((t & 63) == 0)
          S.f.skey[0][par][w] =
              ((unsigned long long)__float_as_uint(wv) << 32) | (unsigned int)~selIdx;
      }
      // ---- reduce B ----
      {
        float m = mB;
        m = dpp_max<0x111>(m); m = dpp_max<0x112>(m); m = dpp_max<0x114>(m);
        m = dpp_max<0x118>(m); m = dpp_max<0x142>(m); m = dpp_max<0x143>(m);
        const float wv = __int_as_float(__builtin_amdgcn_readlane(__float_as_int(m), 63));
        unsigned long long mk[2][4];
#pragma unroll
        for (int k = 0; k < 2; ++k) {
          mk[k][0] = __ballot(dist[k * 4 + 0][1] == wv);
          mk[k][1] = __ballot(dist[k * 4 + 1][1] == wv);
          mk[k][2] = __ballot(dist[k * 4 + 2][1] == wv);
          mk[k][3] = __ballot(dist[k * 4 + 3][1] == wv);
        }
        unsigned long long s0 = 0, s1 = 0, s2 = 0, s3 = 0, anyk = 0;
        int sk = -1;
#pragma unroll
        for (int k = 0; k < 2; ++k) {
          unsigned long long a = mk[k][0] | mk[k][1] | mk[k][2] | mk[k][3];
          if (sk < 0 && a != 0ull) {
            sk = k; anyk = a;
            s0 = mk[k][0]; s1 = mk[k][1]; s2 = mk[k][2]; s3 = mk[k][3];
          }
        }
        const int l = __builtin_ctzll(anyk);
        const unsigned long long bit = 1ull << l;
        const int c = (s0 & bit) ? 0 : (s1 & bit) ? 1 : (s2 & bit) ? 2 : 3;
        const int selIdx = sk * 2048 + 256 * w + 4 * l + c;
        if ((t & 63) == 0)
          S.f.skey[1][par][w] =
              ((unsigned long long)__float_as_uint(wv) << 32) | (unsigned int)~selIdx;
      }
      __syncthreads();

      // ---- 8-key tournaments (parallel non-volatile broadcast reads) ----
      {
        unsigned long long k0 = S.f.skey[0][par][0], k1 = S.f.skey[0][par][1];
        unsigned long long k2 = S.f.skey[0][par][2], k3 = S.f.skey[0][par][3];
        unsigned long long k4 = S.f.skey[0][par][4], k5 = S.f.skey[0][par][5];
        unsigned long long k6 = S.f.skey[0][par][6], k7 = S.f.skey[0][par][7];
        unsigned long long ka = (k0 > k1) ? k0 : k1, kb = (k2 > k3) ? k2 : k3;
        unsigned long long kc = (k4 > k5) ? k4 : k5, kd = (k6 > k7) ? k6 : k7;
        unsigned long long ke = (ka > kb) ? ka : kb, kf = (kc > kd) ? kc : kd;
        unsigned long long km = (ke > kf) ? ke : kf;
        const int selA = (int)(~(unsigned int)km);
        lxA = S.f.sxA[selA]; lyA = S.f.syA[selA]; lzA = S.f.szA[selA];
      }
      {
        unsigned long long k0 = S.f.skey[1][par][0], k1 = S.f.skey[1][par][1];
        unsigned long long k2 = S.f.skey[1][par][2], k3 = S.f.skey[1][par][3];
        unsigned long long k4 = S.f.skey[1][par][4], k5 = S.f.skey[1][par][5];
        unsigned long long k6 = S.f.skey[1][par][6], k7 = S.f.skey[1][par][7];
        unsigned long long ka = (k0 > k1) ? k0 : k1, kb = (k2 > k3) ? k2 : k3;
        unsigned long long kc = (k4 > k5) ? k4 : k5, kd = (k6 > k7) ? k6 : k7;
        unsigned long long ke = (ka > kb) ? ka : kb, kf = (kc > kd) ? kc : kd;
        unsigned long long km = (ke > kf) ? ke : kf;
        const int sB = __builtin_amdgcn_readfirstlane((int)(~(unsigned int)km));
        lxB = pB[sB]; lyB = pB[NPTS + sB]; lzB = pB[2 * NPTS + sB];
      }
    }
  } else if (blk < 8 + 512) {
    // ================== feature transpose (64c x 128n tiles) ==================
    const int rel = blk - 8;
    const int b = rel >> 5;
    const int n0 = (rel & 31) * 128;
    const float* src = feats + (size_t)b * 64 * NPTS;
    {
      const int n = t & 127, cbase = t >> 7;   // cbase 0..3
#pragma unroll
      for (int j = 0; j < 16; ++j) {
        int cc = cbase + j * 4;
        S.tr.tile[cc][n] = src[(size_t)cc * NPTS + n0 + n];
      }
    }
    __syncthreads();
    {
      const int cc = t & 63, nbase = t >> 6;   // nbase 0..7
      unsigned short* dst = featsT + ((size_t)b * NPTS + n0) * 64;
#pragma unroll
      for (int j = 0; j < 16; ++j) {
        int n = nbase + j * 8;
        dst[(size_t)n * 64 + cc] = f2bf(S.tr.tile[cc][n]);
      }
    }
  } else {
    // ================== weight pack (f = 0..35) ==================
    const int f = (blk - (8 + 512)) * 8 + (t >> 6);
    const int lane = t & 63;
    if (f < 36) {
      int layer, kt, nt;
      if (f < 12)      { layer = 0; kt = f >> 2;        nt = f & 3; }
      else if (f < 20) { layer = 1; kt = (f - 12) >> 2; nt = (f - 12) & 3; }
      else             { layer = 2; kt = (f - 20) >> 3; nt = (f - 20) & 7; }
      const int o = nt * 16 + (lane & 15);
      unsigned short* dst = wpack + ((size_t)f * 64 + lane) * 8;
#pragma unroll
      for (int j = 0; j < 8; ++j) {
        int k = kt * 32 + (lane >> 4) * 8 + j;
        float x = 0.0f;
        if (layer == 0)      { if (k < 67) { int cin = (k < 64) ? (k + 3) : (k - 64); x = w1[o * 67 + cin]; } }
        else if (layer == 1) { x = w2[o * 64 + k]; }
        else                 { x = w3[o * 64 + k]; }
        dst[j] = f2bf(x);
      }
    }
  }
}

// ---------------------------------------------------------------------------
// Kernel 2: ball query. Centroids read from out_cent layout [B,3,MC].
// ---------------------------------------------------------------------------
__global__ __launch_bounds__(256) void ball_query_kernel(const float* __restrict__ points,
                                                         const float* __restrict__ cent,
                                                         int* __restrict__ nidx) {
  __shared__ float sx[NPTS], sy[NPTS], sz[NPTS];
  __shared__ int lists[4][KNB];
  const int b  = blockIdx.x >> 4;
  const int cb = blockIdx.x & 15;
  const int t = threadIdx.x;
  const float* pb = points + (size_t)b * 3 * NPTS;
#pragma unroll
  for (int j = 0; j < 4; ++j) {
    int i4 = t + j * 256;
    ((float4*)sx)[i4] = ((const float4*)pb)[i4];
    ((float4*)sy)[i4] = ((const float4*)(pb + NPTS))[i4];
    ((float4*)sz)[i4] = ((const float4*)(pb + 2 * NPTS))[i4];
  }
  __syncthreads();
  const int w = t >> 6, lane = t & 63;
  const float R2 = (float)(0.2 * 0.2);
  const float* cbp = cent + (size_t)b * 3 * MC;
  for (int cm = 0; cm < 16; ++cm) {
    const int m  = cb * 64 + w * 16 + cm;
    const int bm = b * MC + m;
    const float cx = cbp[m], cy = cbp[MC + m], cz = cbp[2 * MC + m];
    const float c2 = __fadd_rn(__fadd_rn(__fmul_rn(cx, cx), __fmul_rn(cy, cy)), __fmul_rn(cz, cz));
    int cnt = 0;
    for (int ch = 0; ch < 64; ++ch) {
      const int n = ch * 64 + lane;
      float x = sx[n], y = sy[n], z = sz[n];
      float p2  = __fadd_rn(__fadd_rn(__fmul_rn(x, x),  __fmul_rn(y, y)),  __fmul_rn(z, z));
      float dot = __fadd_rn(__fadd_rn(__fmul_rn(cx, x), __fmul_rn(cy, y)), __fmul_rn(cz, z));
      float d2  = __fsub_rn(__fadd_rn(c2, p2), __fmul_rn(2.0f, dot));
      bool hit = (d2 <= R2);
      unsigned long long msk = __ballot(hit);
      if (hit) {
        int pos = cnt + __popcll(msk & ((1ull << lane) - 1ull));
        if (pos < KNB) lists[w][pos] = n;
      }
      cnt += __popcll(msk);
      if (cnt >= KNB) break;
    }
    if (lane < KNB) {
      int first = lists[w][0];
      int v = (lane < cnt) ? lists[w][lane] : first;
      nidx[(size_t)bm * KNB + lane] = v;
    }
  }
}

// ---------------------------------------------------------------------------
// Kernel 3: fused gather + 3-layer MLP (bf16 MFMA 16x16x32) + maxpool.
// ---------------------------------------------------------------------------
__global__ __launch_bounds__(256) void mlp_kernel(
    const float* __restrict__ points,
    const float* __restrict__ cent,
    const int* __restrict__ nidx,
    const unsigned short* __restrict__ featsT,
    const unsigned short* __restrict__ wpack,
    const float* __restrict__ b1, const float* __restrict__ g1, const float* __restrict__ be1,
    const float* __restrict__ b2, const float* __restrict__ g2, const float* __restrict__ be2,
    const float* __restrict__ b3, const float* __restrict__ g3, const float* __restrict__ be3,
    float* __restrict__ out) {
  __shared__ __align__(16) unsigned short Hs[4][2][32 * 72];
  __shared__ __align__(16) float obuf[128 * 20];
  const int t = threadIdx.x;
  const int w = t >> 6, lane = t & 63;
  const int r = lane & 15, q = lane >> 4;
  const float inv_s = 1.0f / sqrtf(1.0f + 1e-5f);

  float pb1[4], ps1[4], pe1[4], pb2[4], ps2[4], pe2[4], pb3[8], ps3[8], pe3[8];
#pragma unroll
  for (int nt = 0; nt < 4; ++nt) {
    int o = nt * 16 + r;
    pb1[nt] = b1[o]; ps1[nt] = g1[o] * inv_s; pe1[nt] = be1[o];
    pb2[nt] = b2[o]; ps2[nt] = g2[o] * inv_s; pe2[nt] = be2[o];
  }
#pragma unroll
  for (int nt = 0; nt < 8; ++nt) {
    int o = nt * 16 + r;
    pb3[nt] = b3[o]; ps3[nt] = g3[o] * inv_s; pe3[nt] = be3[o];
  }
  const int bm0 = blockIdx.x * 16;
  const int b   = bm0 >> 10;
  const int m0  = bm0 & 1023;
  const float* ptsb = points + (size_t)b * 3 * NPTS;
  const float* cbp  = cent + (size_t)b * 3 * MC;

  for (int it = 0; it < 4; ++it) {
    const int ml = it * 4 + w;
    const int bm = bm0 + ml;
    const int m  = bm & 1023;
    const int n0 = nidx[(size_t)bm * KNB + r];
    const int n1 = nidx[(size_t)bm * KNB + 16 + r];
    const float cx = cbp[m], cy = cbp[MC + m], cz = cbp[2 * MC + m];

    // ---- layer 1 ----
    bf16x8 aF[2][2];
#pragma unroll
    for (int mt = 0; mt < 2; ++mt) {
      int n = mt ? n1 : n0;
      const unsigned short* rowp = featsT + ((size_t)b * NPTS + n) * 64 + q * 8;
      aF[mt][0] = *(const bf16x8*)(rowp);
      aF[mt][1] = *(const bf16x8*)(rowp + 32);
    }
    bf16x8 aL[2];
#pragma unroll
    for (int mt = 0; mt < 2; ++mt) {
      bf16x8 a = {0, 0, 0, 0, 0, 0, 0, 0};
      if (q == 0) {
        int n = mt ? n1 : n0;
        a[0] = (short)f2bf(ptsb[n] - cx);
        a[1] = (short)f2bf(ptsb[NPTS + n] - cy);
        a[2] = (short)f2bf(ptsb[2 * NPTS + n] - cz);
      }
      aL[mt] = a;
    }
    f32x4 acc1[2][4];
#pragma unroll
    for (int mt = 0; mt < 2; ++mt)
#pragma unroll
      for (int nt = 0; nt < 4; ++nt) acc1[mt][nt] = (f32x4){0.f, 0.f, 0.f, 0.f};
#pragma unroll
    for (int kt = 0; kt < 3; ++kt) {
#pragma unroll
      for (int nt = 0; nt < 4; ++nt) {
        bf16x8 wf = *(const bf16x8*)(wpack + ((size_t)(kt * 4 + nt) * 64 + lane) * 8);
#pragma unroll
        for (int mt = 0; mt < 2; ++mt) {
          bf16x8 a = (kt < 2) ? aF[mt][kt] : aL[mt];
          acc1[mt][nt] = __builtin_amdgcn_mfma_f32_16x16x32_bf16(a, wf, acc1[mt][nt], 0, 0, 0);
        }
      }
    }
#pragma unroll
    for (int mt = 0; mt < 2; ++mt)
#pragma unroll
      for (int nt = 0; nt < 4; ++nt)
#pragma unroll
        for (int rr = 0; rr < 4; ++rr) {
          float y = (acc1[mt][nt][rr] + pb1[nt]) * ps1[nt] + pe1[nt];
          y = fmaxf(y, 0.0f);
          Hs[w][0][(mt * 16 + q * 4 + rr) * 72 + nt * 16 + r] = f2bf(y);
        }
    __threadfence_block();

    // ---- layer 2 ----
    f32x4 acc2[2][4];
#pragma unroll
    for (int mt = 0; mt < 2; ++mt)
#pragma unroll
      for (int nt = 0; nt < 4; ++nt) acc2[mt][nt] = (f32x4){0.f, 0.f, 0.f, 0.f};
#pragma unroll
    for (int kt = 0; kt < 2; ++kt) {
      bf16x8 a0 = *(const bf16x8*)&Hs[w][0][(0 * 16 + r) * 72 + kt * 32 + q * 8];
      bf16x8 a1 = *(const bf16x8*)&Hs[w][0][(1 * 16 + r) * 72 + kt * 32 + q * 8];
#pragma unroll
      for (int nt = 0; nt < 4; ++nt) {
        bf16x8 wf = *(const bf16x8*)(wpack + ((size_t)(12 + kt * 4 + nt) * 64 + lane) * 8);
        acc2[0][nt] = __builtin_amdgcn_mfma_f32_16x16x32_bf16(a0, wf, acc2[0][nt], 0, 0, 0);
        acc2[1][nt] = __builtin_amdgcn_mfma_f32_16x16x32_bf16(a1, wf, acc2[1][nt], 0, 0, 0);
      }
    }
#pragma unroll
    for (int mt = 0; mt < 2; ++mt)
#pragma unroll
      for (int nt = 0; nt < 4; ++nt)
#pragma unroll
        for (int rr = 0; rr < 4; ++rr) {
          float y = (acc2[mt][nt][rr] + pb2[nt]) * ps2[nt] + pe2[nt];
          y = fmaxf(y, 0.0f);
          Hs[w][1][(mt * 16 + q * 4 + rr) * 72 + nt * 16 + r] = f2bf(y);
        }
    __threadfence_block();

    // ---- layer 3 + maxpool ----
    f32x4 acc3[2][8];
#pragma unroll
    for (int mt = 0; mt < 2; ++mt)
#pragma unroll
      for (int nt = 0; nt < 8; ++nt) acc3[mt][nt] = (f32x4){0.f, 0.f, 0.f, 0.f};
#pragma unroll
    for (int kt = 0; kt < 2; ++kt) {
      bf16x8 a0 = *(const bf16x8*)&Hs[w][1][(0 * 16 + r) * 72 + kt * 32 + q * 8];
      bf16x8 a1 = *(const bf16x8*)&Hs[w][1][(1 * 16 + r) * 72 + kt * 32 + q * 8];
#pragma unroll
      for (int nt = 0; nt < 8; ++nt) {
        bf16x8 wf = *(const bf16x8*)(wpack + ((size_t)(20 + kt * 8 + nt) * 64 + lane) * 8);
        acc3[0][nt] = __builtin_amdgcn_mfma_f32_16x16x32_bf16(a0, wf, acc3[0][nt], 0, 0, 0);
        acc3[1][nt] = __builtin_amdgcn_mfma_f32_16x16x32_bf16(a1, wf, acc3[1][nt], 0, 0, 0);
      }
    }
#pragma unroll
    for (int nt = 0; nt < 8; ++nt) {
      float pm = 0.0f;   // relu outputs are >= 0
#pragma unroll
      for (int mt = 0; mt < 2; ++mt)
#pragma unroll
        for (int rr = 0; rr < 4; ++rr) {
          float y = (acc3[mt][nt][rr] + pb3[nt]) * ps3[nt] + pe3[nt];
          y = fmaxf(y, 0.0f);
          pm = fmaxf(pm, y);
        }
      pm = fmaxf(pm, __shfl_xor(pm, 16));
      pm = fmaxf(pm, __shfl_xor(pm, 32));
      if (q == 0) obuf[(nt * 16 + r) * 20 + ml] = pm;
    }
    __threadfence_block();
  }
  __syncthreads();
  // coalesced-ish store: thread t -> channel t>>1, half (t&1)*8
  {
    const int ch = t >> 1, mh = (t & 1) * 8;
    float4 u0 = *(const float4*)&obuf[ch * 20 + mh];
    float4 u1 = *(const float4*)&obuf[ch * 20 + mh + 4];
    float* outp = out + ((size_t)b * 128 + ch) * 1024 + m0 + mh;
    *(float4*)(outp)     = u0;
    *(float4*)(outp + 4) = u1;
  }
}

// ---------------------------------------------------------------------------
extern "C" void kernel_launch(void* const* d_in, const int* in_sizes, int n_in,
                              void* d_out, int out_size, void* d_ws, size_t ws_size,
                              hipStream_t stream) {
  (void)in_sizes; (void)n_in; (void)out_size; (void)ws_size;
  const float* points   = (const float*)d_in[0];
  const float* features = (const float*)d_in[1];
  const float* w1  = (const float*)d_in[2];
  const float* b1  = (const float*)d_in[3];
  const float* g1  = (const float*)d_in[4];
  const float* be1 = (const float*)d_in[5];
  const float* w2  = (const float*)d_in[6];
  const float* b2  = (const float*)d_in[7];
  const float* g2  = (const float*)d_in[8];
  const float* be2 = (const float*)d_in[9];
  const float* w3  = (const float*)d_in[10];
  const float* b3  = (const float*)d_in[11];
  const float* g3  = (const float*)d_in[12];
  const float* be3 = (const float*)d_in[13];

  float* outc = (float*)d_out;                  // centroids [16,3,1024]
  float* outf = outc + 16 * 3 * 1024;           // features  [16,128,1024]

  char* ws = (char*)d_ws;
  int*            nidx    = (int*)(ws);                      // 16384*32*4  = 2 MiB
  unsigned short* featsT  = (unsigned short*)(ws + 0x200000);// 16*4096*64*2= 8 MiB
  unsigned short* wpack   = (unsigned short*)(ws + 0xA00000);// 36*1024 B

  fused_pre<<<8 + 512 + 5, 512, 0, stream>>>(points, features, w1, w2, w3,
                                             featsT, wpack, outc);
  ball_query_kernel<<<256, 256, 0, stream>>>(points, outc, nidx);
  mlp_kernel<<<1024, 256, 0, stream>>>(points, outc, nidx, featsT, wpack,
                                       b1, g1, be1, b2, g2, be2, b3, g3, be3, outf);
}

// Round 8
// 949.296 us; speedup vs baseline: 1.9653x; 1.9653x over previous
//
#include <hip/hip_runtime.h>
#include <math.h>

#define NPTS 4096
#define MC   1024
#define KNB  32

typedef __attribute__((ext_vector_type(8))) short bf16x8;
typedef __attribute__((ext_vector_type(4))) float f32x4;
typedef __attribute__((ext_vector_type(2))) float f32x2;

__device__ __forceinline__ unsigned short f2bf(float f) {
  unsigned int u = __float_as_uint(f);
  u = u + 0x7fffu + ((u >> 16) & 1u);   // round-to-nearest-even
  return (unsigned short)(u >> 16);
}

template <int CTRL>
__device__ __forceinline__ float dpp_max(float v) {
  int o = __builtin_amdgcn_update_dpp(__float_as_int(v), __float_as_int(v), CTRL, 0xF, 0xF, false);
  return fmaxf(v, __int_as_float(o));
}

// ---------------------------------------------------------------------------
// Kernel 1 (fused): blocks 0..15 = FPS, 16..1039 = feature transpose,
// 1040..1048 = weight pack. == R6 VERBATIM (the session's banked 950us WIN,
// fused_pre 670us, VGPR=88 resident) ==
//
// FPS: 256 thr (4 waves, 1/SIMD), 16 pts/lane held as f32x2[8] packed state
// (v_pk_add/mul update, contract(off) -> elementwise IEEE rn, bit-exact).
// Value-only DPP wave64 max -> readlane(63) -> 16 ballots + SALU scan
// (exact lowest-index tie-break) -> lane0 publishes u64 key (dist<<32|~idx)
// to parity-double-buffered slot -> ONE barrier -> 4-key tournament ->
// LDS broadcast coord fetch.
//
// SESSION LEDGER (all counter-verified; do NOT revisit):
//   R1  8-wave single batch        -> lockstep barrier cost (+138us)
//   R2  barrier-free volatile spin -> serialized LDS reads (+640us)
//   R3  scalar batch-pair          -> spill @ VGPR=116
//   R4  MUX16 register payload     -> spill @ VGPR=64
//   R5  value-only scalar pair     -> spill @ VGPR=44
//   R6  packed f32x2 update        -> WIN 702->670us, VGPR=88 resident
//   R7  packed f32x2 batch-pair    -> spill @ VGPR=48 (dual reduce contexts
//       push peak liveness over the cliff; pairing family is dead)
// Remaining per-iter ~1330cyc is the dependent DPP->readlane->ballot->scan->
// LDS->barrier->LDS->LDS chain at 1 wave/SIMD; each component individually
// minimal. Next lever would be FPS->consumer streaming overlap (device-scope
// progress flags), rejected: correctness would depend on undefined block
// dispatch order (hang risk).
// ---------------------------------------------------------------------------
struct FpsShared {
  float sx[NPTS], sy[NPTS], sz[NPTS];
  unsigned long long skey[2][4];
  float slog[3][MC];
};
struct TransShared {
  float tile[64][65];
};

__global__ __launch_bounds__(256, 1) void fused_pre(
    const float* __restrict__ points, const float* __restrict__ feats,
    const float* __restrict__ w1, const float* __restrict__ w2,
    const float* __restrict__ w3,
    unsigned short* __restrict__ featsT, unsigned short* __restrict__ wpack,
    float* __restrict__ out_cent) {
  __shared__ union { FpsShared f; TransShared tr; } S;
  const int blk = blockIdx.x;
  const int t = threadIdx.x;

  if (blk < 16) {
    // ======================= FPS =======================
    const int b = blk;
    const int w = t >> 6;
    const float* pb = points + (size_t)b * 3 * NPTS;

    // lane-owned idx for (k,c) = k*1024 + 4*t + c ; packed pair p=k*2+(c>>1),
    // element c&1 holds scalar point (k,c).
    f32x2 fx[8], fy[8], fz[8], dist[8];
#pragma unroll
    for (int k = 0; k < 4; ++k) {
      float4 X = ((const float4*)pb)[k * 256 + t];
      float4 Y = ((const float4*)(pb + NPTS))[k * 256 + t];
      float4 Z = ((const float4*)(pb + 2 * NPTS))[k * 256 + t];
      ((float4*)S.f.sx)[k * 256 + t] = X;
      ((float4*)S.f.sy)[k * 256 + t] = Y;
      ((float4*)S.f.sz)[k * 256 + t] = Z;
      fx[k * 2 + 0] = (f32x2){X.x, X.y}; fx[k * 2 + 1] = (f32x2){X.z, X.w};
      fy[k * 2 + 0] = (f32x2){Y.x, Y.y}; fy[k * 2 + 1] = (f32x2){Y.z, Y.w};
      fz[k * 2 + 0] = (f32x2){Z.x, Z.y}; fz[k * 2 + 1] = (f32x2){Z.z, Z.w};
    }
#pragma unroll
    for (int p = 0; p < 8; ++p) dist[p] = (f32x2){1e10f, 1e10f};
    __syncthreads();

    float lx = S.f.sx[0], ly = S.f.sy[0], lz = S.f.sz[0];

    for (int i = 0; i < MC; ++i) {
      if (t == 0) { S.f.slog[0][i] = lx; S.f.slog[1][i] = ly; S.f.slog[2][i] = lz; }
      if (i == MC - 1) break;

      // ---- packed distance update (bit-exact: contract off, elementwise
      //      IEEE rn == scalar __f*_rn chain) + per-lane max ----
      float m0, m1;
      {
#pragma clang fp contract(off)
        const f32x2 Lx = {lx, lx};
        const f32x2 Ly = {ly, ly};
        const f32x2 Lz = {lz, lz};
        m0 = -1.0f; m1 = -1.0f;
#pragma unroll
        for (int p = 0; p < 8; ++p) {
          f32x2 dx = fx[p] - Lx;
          f32x2 dy = fy[p] - Ly;
          f32x2 dz = fz[p] - Lz;
          f32x2 d  = dx * dx + dy * dy + dz * dz;   // pk_mul + pk_add, no fma
          float dm0 = fminf(dist[p][0], d[0]);
          float dm1 = fminf(dist[p][1], d[1]);
          dist[p][0] = dm0;
          dist[p][1] = dm1;
          m0 = fmaxf(m0, dm0);
          m1 = fmaxf(m1, dm1);
        }
      }
      float m = fmaxf(m0, m1);

      // ---- value-only wave64 max via DPP (result in lane 63) ----
      m = dpp_max<0x111>(m);   // row_shr:1
      m = dpp_max<0x112>(m);   // row_shr:2
      m = dpp_max<0x114>(m);   // row_shr:4
      m = dpp_max<0x118>(m);   // row_shr:8
      m = dpp_max<0x142>(m);   // row_bcast:15
      m = dpp_max<0x143>(m);   // row_bcast:31
      const float wv = __int_as_float(__builtin_amdgcn_readlane(__float_as_int(m), 63));

      // ---- recover lowest matching index: 16 ballots + SALU scan ----
      // global idx = k*1024 + 4*(w*64+lane) + c: scan k asc, then lowest
      // lane (ctz), then lowest c — exact lowest-index tie-break.
      unsigned long long mk[4][4];
#pragma unroll
      for (int k = 0; k < 4; ++k) {
        mk[k][0] = __ballot(dist[k * 2 + 0][0] == wv);
        mk[k][1] = __ballot(dist[k * 2 + 0][1] == wv);
        mk[k][2] = __ballot(dist[k * 2 + 1][0] == wv);
        mk[k][3] = __ballot(dist[k * 2 + 1][1] == wv);
      }
      unsigned long long s0 = 0, s1 = 0, s2 = 0, s3 = 0, anyk = 0;
      int sk = -1;
#pragma unroll
      for (int k = 0; k < 4; ++k) {
        unsigned long long a = mk[k][0] | mk[k][1] | mk[k][2] | mk[k][3];
        if (sk < 0 && a != 0ull) {
          sk = k; anyk = a;
          s0 = mk[k][0]; s1 = mk[k][1]; s2 = mk[k][2]; s3 = mk[k][3];
        }
      }
      const int l = __builtin_ctzll(anyk);
      const unsigned long long bit = 1ull << l;
      const int c = (s0 & bit) ? 0 : (s1 & bit) ? 1 : (s2 & bit) ? 2 : 3;
      const int selIdx = sk * 1024 + 256 * w + 4 * l + c;

      const int nb = i & 1;
      if ((t & 63) == 0)
        S.f.skey[nb][w] = ((unsigned long long)__float_as_uint(wv) << 32) | (unsigned int)~selIdx;
      __syncthreads();

      // ---- all lanes: max of 4 keys, then LDS broadcast of winner coords ----
      unsigned long long k0 = S.f.skey[nb][0], k1 = S.f.skey[nb][1];
      unsigned long long k2 = S.f.skey[nb][2], k3 = S.f.skey[nb][3];
      unsigned long long ka = (k0 > k1) ? k0 : k1;
      unsigned long long kb = (k2 > k3) ? k2 : k3;
      unsigned long long km = (ka > kb) ? ka : kb;
      const int sel = (int)(~(unsigned int)km);
      lx = S.f.sx[sel]; ly = S.f.sy[sel]; lz = S.f.sz[sel];
    }
    __syncthreads();
    // coalesced centroid output [3][1024] per batch
    float* oc = out_cent + (size_t)b * 3 * MC;
#pragma unroll
    for (int k = 0; k < 12; ++k) {
      int idx = t + k * 256;
      oc[idx] = ((const float*)S.f.slog)[idx];
    }
  } else if (blk < 16 + 1024) {
    // ================== feature transpose ==================
    const int rel = blk - 16;
    const int b = rel >> 6;
    const int n0 = (rel & 63) * 64;
    const float* src = feats + (size_t)b * 64 * NPTS;
    {
      const int n = t & 63, cbase = t >> 6;
#pragma unroll
      for (int j = 0; j < 16; ++j) {
        int cc = cbase + j * 4;
        S.tr.tile[cc][n] = src[(size_t)cc * NPTS + n0 + n];
      }
    }
    __syncthreads();
    {
      const int cc = t & 63, nbase = t >> 6;
      unsigned short* dst = featsT + ((size_t)b * NPTS + n0) * 64;
#pragma unroll
      for (int j = 0; j < 16; ++j) {
        int n = nbase + j * 4;
        dst[(size_t)n * 64 + cc] = f2bf(S.tr.tile[cc][n]);
      }
    }
  } else {
    // ================== weight pack (f = 0..35) ==================
    const int f = (blk - (16 + 1024)) * 4 + (t >> 6);
    const int lane = t & 63;
    if (f < 36) {
      int layer, kt, nt;
      if (f < 12)      { layer = 0; kt = f >> 2;        nt = f & 3; }
      else if (f < 20) { layer = 1; kt = (f - 12) >> 2; nt = (f - 12) & 3; }
      else             { layer = 2; kt = (f - 20) >> 3; nt = (f - 20) & 7; }
      const int o = nt * 16 + (lane & 15);
      unsigned short* dst = wpack + ((size_t)f * 64 + lane) * 8;
#pragma unroll
      for (int j = 0; j < 8; ++j) {
        int k = kt * 32 + (lane >> 4) * 8 + j;
        float x = 0.0f;
        if (layer == 0)      { if (k < 67) { int cin = (k < 64) ? (k + 3) : (k - 64); x = w1[o * 67 + cin]; } }
        else if (layer == 1) { x = w2[o * 64 + k]; }
        else                 { x = w3[o * 64 + k]; }
        dst[j] = f2bf(x);
      }
    }
  }
}

// ---------------------------------------------------------------------------
// Kernel 2: ball query. Centroids read from out_cent layout [B,3,MC].
// ---------------------------------------------------------------------------
__global__ __launch_bounds__(256) void ball_query_kernel(const float* __restrict__ points,
                                                         const float* __restrict__ cent,
                                                         int* __restrict__ nidx) {
  __shared__ float sx[NPTS], sy[NPTS], sz[NPTS];
  __shared__ int lists[4][KNB];
  const int b  = blockIdx.x >> 4;
  const int cb = blockIdx.x & 15;
  const int t = threadIdx.x;
  const float* pb = points + (size_t)b * 3 * NPTS;
#pragma unroll
  for (int j = 0; j < 4; ++j) {
    int i4 = t + j * 256;
    ((float4*)sx)[i4] = ((const float4*)pb)[i4];
    ((float4*)sy)[i4] = ((const float4*)(pb + NPTS))[i4];
    ((float4*)sz)[i4] = ((const float4*)(pb + 2 * NPTS))[i4];
  }
  __syncthreads();
  const int w = t >> 6, lane = t & 63;
  const float R2 = (float)(0.2 * 0.2);
  const float* cbp = cent + (size_t)b * 3 * MC;
  for (int cm = 0; cm < 16; ++cm) {
    const int m  = cb * 64 + w * 16 + cm;
    const int bm = b * MC + m;
    const float cx = cbp[m], cy = cbp[MC + m], cz = cbp[2 * MC + m];
    const float c2 = __fadd_rn(__fadd_rn(__fmul_rn(cx, cx), __fmul_rn(cy, cy)), __fmul_rn(cz, cz));
    int cnt = 0;
    for (int ch = 0; ch < 64; ++ch) {
      const int n = ch * 64 + lane;
      float x = sx[n], y = sy[n], z = sz[n];
      float p2  = __fadd_rn(__fadd_rn(__fmul_rn(x, x),  __fmul_rn(y, y)),  __fmul_rn(z, z));
      float dot = __fadd_rn(__fadd_rn(__fmul_rn(cx, x), __fmul_rn(cy, y)), __fmul_rn(cz, z));
      float d2  = __fsub_rn(__fadd_rn(c2, p2), __fmul_rn(2.0f, dot));
      bool hit = (d2 <= R2);
      unsigned long long msk = __ballot(hit);
      if (hit) {
        int pos = cnt + __popcll(msk & ((1ull << lane) - 1ull));
        if (pos < KNB) lists[w][pos] = n;
      }
      cnt += __popcll(msk);
      if (cnt >= KNB) break;
    }
    if (lane < KNB) {
      int first = lists[w][0];
      int v = (lane < cnt) ? lists[w][lane] : first;
      nidx[(size_t)bm * KNB + lane] = v;
    }
  }
}

// ---------------------------------------------------------------------------
// Kernel 3: fused gather + 3-layer MLP (bf16 MFMA 16x16x32) + maxpool.
// ---------------------------------------------------------------------------
__global__ __launch_bounds__(256) void mlp_kernel(
    const float* __restrict__ points,
    const float* __restrict__ cent,
    const int* __restrict__ nidx,
    const unsigned short* __restrict__ featsT,
    const unsigned short* __restrict__ wpack,
    const float* __restrict__ b1, const float* __restrict__ g1, const float* __restrict__ be1,
    const float* __restrict__ b2, const float* __restrict__ g2, const float* __restrict__ be2,
    const float* __restrict__ b3, const float* __restrict__ g3, const float* __restrict__ be3,
    float* __restrict__ out) {
  __shared__ __align__(16) unsigned short Hs[4][2][32 * 72];
  __shared__ __align__(16) float obuf[128 * 20];
  const int t = threadIdx.x;
  const int w = t >> 6, lane = t & 63;
  const int r = lane & 15, q = lane >> 4;
  const float inv_s = 1.0f / sqrtf(1.0f + 1e-5f);

  float pb1[4], ps1[4], pe1[4], pb2[4], ps2[4], pe2[4], pb3[8], ps3[8], pe3[8];
#pragma unroll
  for (int nt = 0; nt < 4; ++nt) {
    int o = nt * 16 + r;
    pb1[nt] = b1[o]; ps1[nt] = g1[o] * inv_s; pe1[nt] = be1[o];
    pb2[nt] = b2[o]; ps2[nt] = g2[o] * inv_s; pe2[nt] = be2[o];
  }
#pragma unroll
  for (int nt = 0; nt < 8; ++nt) {
    int o = nt * 16 + r;
    pb3[nt] = b3[o]; ps3[nt] = g3[o] * inv_s; pe3[nt] = be3[o];
  }
  const int bm0 = blockIdx.x * 16;
  const int b   = bm0 >> 10;
  const int m0  = bm0 & 1023;
  const float* ptsb = points + (size_t)b * 3 * NPTS;
  const float* cbp  = cent + (size_t)b * 3 * MC;

  for (int it = 0; it < 4; ++it) {
    const int ml = it * 4 + w;
    const int bm = bm0 + ml;
    const int m  = bm & 1023;
    const int n0 = nidx[(size_t)bm * KNB + r];
    const int n1 = nidx[(size_t)bm * KNB + 16 + r];
    const float cx = cbp[m], cy = cbp[MC + m], cz = cbp[2 * MC + m];

    // ---- layer 1 ----
    bf16x8 aF[2][2];
#pragma unroll
    for (int mt = 0; mt < 2; ++mt) {
      int n = mt ? n1 : n0;
      const unsigned short* rowp = featsT + ((size_t)b * NPTS + n) * 64 + q * 8;
      aF[mt][0] = *(const bf16x8*)(rowp);
      aF[mt][1] = *(const bf16x8*)(rowp + 32);
    }
    bf16x8 aL[2];
#pragma unroll
    for (int mt = 0; mt < 2; ++mt) {
      bf16x8 a = {0, 0, 0, 0, 0, 0, 0, 0};
      if (q == 0) {
        int n = mt ? n1 : n0;
        a[0] = (short)f2bf(ptsb[n] - cx);
        a[1] = (short)f2bf(ptsb[NPTS + n] - cy);
        a[2] = (short)f2bf(ptsb[2 * NPTS + n] - cz);
      }
      aL[mt] = a;
    }
    f32x4 acc1[2][4];
#pragma unroll
    for (int mt = 0; mt < 2; ++mt)
#pragma unroll
      for (int nt = 0; nt < 4; ++nt) acc1[mt][nt] = (f32x4){0.f, 0.f, 0.f, 0.f};
#pragma unroll
    for (int kt = 0; kt < 3; ++kt) {
#pragma unroll
      for (int nt = 0; nt < 4; ++nt) {
        bf16x8 wf = *(const bf16x8*)(wpack + ((size_t)(kt * 4 + nt) * 64 + lane) * 8);
#pragma unroll
        for (int mt = 0; mt < 2; ++mt) {
          bf16x8 a = (kt < 2) ? aF[mt][kt] : aL[mt];
          acc1[mt][nt] = __builtin_amdgcn_mfma_f32_16x16x32_bf16(a, wf, acc1[mt][nt], 0, 0, 0);
        }
      }
    }
#pragma unroll
    for (int mt = 0; mt < 2; ++mt)
#pragma unroll
      for (int nt = 0; nt < 4; ++nt)
#pragma unroll
        for (int rr = 0; rr < 4; ++rr) {
          float y = (acc1[mt][nt][rr] + pb1[nt]) * ps1[nt] + pe1[nt];
          y = fmaxf(y, 0.0f);
          Hs[w][0][(mt * 16 + q * 4 + rr) * 72 + nt * 16 + r] = f2bf(y);
        }
    __threadfence_block();

    // ---- layer 2 ----
    f32x4 acc2[2][4];
#pragma unroll
    for (int mt = 0; mt < 2; ++mt)
#pragma unroll
      for (int nt = 0; nt < 4; ++nt) acc2[mt][nt] = (f32x4){0.f, 0.f, 0.f, 0.f};
#pragma unroll
    for (int kt = 0; kt < 2; ++kt) {
      bf16x8 a0 = *(const bf16x8*)&Hs[w][0][(0 * 16 + r) * 72 + kt * 32 + q * 8];
      bf16x8 a1 = *(const bf16x8*)&Hs[w][0][(1 * 16 + r) * 72 + kt * 32 + q * 8];
#pragma unroll
      for (int nt = 0; nt < 4; ++nt) {
        bf16x8 wf = *(const bf16x8*)(wpack + ((size_t)(12 + kt * 4 + nt) * 64 + lane) * 8);
        acc2[0][nt] = __builtin_amdgcn_mfma_f32_16x16x32_bf16(a0, wf, acc2[0][nt], 0, 0, 0);
        acc2[1][nt] = __builtin_amdgcn_mfma_f32_16x16x32_bf16(a1, wf, acc2[1][nt], 0, 0, 0);
      }
    }
#pragma unroll
    for (int mt = 0; mt < 2; ++mt)
#pragma unroll
      for (int nt = 0; nt < 4; ++nt)
#pragma unroll
        for (int rr = 0; rr < 4; ++rr) {
          float y = (acc2[mt][nt][rr] + pb2[nt]) * ps2[nt] + pe2[nt];
          y = fmaxf(y, 0.0f);
          Hs[w][1][(mt * 16 + q * 4 + rr) * 72 + nt * 16 + r] = f2bf(y);
        }
    __threadfence_block();

    // ---- layer 3 + maxpool ----
    f32x4 acc3[2][8];
#pragma unroll
    for (int mt = 0; mt < 2; ++mt)
#pragma unroll
      for (int nt = 0; nt < 8; ++nt) acc3[mt][nt] = (f32x4){0.f, 0.f, 0.f, 0.f};
#pragma unroll
    for (int kt = 0; kt < 2; ++kt) {
      bf16x8 a0 = *(const bf16x8*)&Hs[w][1][(0 * 16 + r) * 72 + kt * 32 + q * 8];
      bf16x8 a1 = *(const bf16x8*)&Hs[w][1][(1 * 16 + r) * 72 + kt * 32 + q * 8];
#pragma unroll
      for (int nt = 0; nt < 8; ++nt) {
        bf16x8 wf = *(const bf16x8*)(wpack + ((size_t)(20 + kt * 8 + nt) * 64 + lane) * 8);
        acc3[0][nt] = __builtin_amdgcn_mfma_f32_16x16x32_bf16(a0, wf, acc3[0][nt], 0, 0, 0);
        acc3[1][nt] = __builtin_amdgcn_mfma_f32_16x16x32_bf16(a1, wf, acc3[1][nt], 0, 0, 0);
      }
    }
#pragma unroll
    for (int nt = 0; nt < 8; ++nt) {
      float pm = 0.0f;   // relu outputs are >= 0
#pragma unroll
      for (int mt = 0; mt < 2; ++mt)
#pragma unroll
        for (int rr = 0; rr < 4; ++rr) {
          float y = (acc3[mt][nt][rr] + pb3[nt]) * ps3[nt] + pe3[nt];
          y = fmaxf(y, 0.0f);
          pm = fmaxf(pm, y);
        }
      pm = fmaxf(pm, __shfl_xor(pm, 16));
      pm = fmaxf(pm, __shfl_xor(pm, 32));
      if (q == 0) obuf[(nt * 16 + r) * 20 + ml] = pm;
    }
    __threadfence_block();
  }
  __syncthreads();
  // coalesced-ish store: thread t -> channel t>>1, half (t&1)*8
  {
    const int ch = t >> 1, mh = (t & 1) * 8;
    float4 u0 = *(const float4*)&obuf[ch * 20 + mh];
    float4 u1 = *(const float4*)&obuf[ch * 20 + mh + 4];
    float* outp = out + ((size_t)b * 128 + ch) * 1024 + m0 + mh;
    *(float4*)(outp)     = u0;
    *(float4*)(outp + 4) = u1;
  }
}

// ---------------------------------------------------------------------------
extern "C" void kernel_launch(void* const* d_in, const int* in_sizes, int n_in,
                              void* d_out, int out_size, void* d_ws, size_t ws_size,
                              hipStream_t stream) {
  (void)in_sizes; (void)n_in; (void)out_size; (void)ws_size;
  const float* points   = (const float*)d_in[0];
  const float* features = (const float*)d_in[1];
  const float* w1  = (const float*)d_in[2];
  const float* b1  = (const float*)d_in[3];
  const float* g1  = (const float*)d_in[4];
  const float* be1 = (const float*)d_in[5];
  const float* w2  = (const float*)d_in[6];
  const float* b2  = (const float*)d_in[7];
  const float* g2  = (const float*)d_in[8];
  const float* be2 = (const float*)d_in[9];
  const float* w3  = (const float*)d_in[10];
  const float* b3  = (const float*)d_in[11];
  const float* g3  = (const float*)d_in[12];
  const float* be3 = (const float*)d_in[13];

  float* outc = (float*)d_out;                  // centroids [16,3,1024]
  float* outf = outc + 16 * 3 * 1024;           // features  [16,128,1024]

  char* ws = (char*)d_ws;
  int*            nidx    = (int*)(ws);                      // 16384*32*4  = 2 MiB
  unsigned short* featsT  = (unsigned short*)(ws + 0x200000);// 16*4096*64*2= 8 MiB
  unsigned short* wpack   = (unsigned short*)(ws + 0xA00000);// 36*1024 B

  fused_pre<<<16 + 1024 + 9, 256, 0, stream>>>(points, features, w1, w2, w3,
                                               featsT, wpack, outc);
  ball_query_kernel<<<256, 256, 0, stream>>>(points, outc, nidx);
  mlp_kernel<<<1024, 256, 0, stream>>>(points, outc, nidx, featsT, wpack,
                                       b1, g1, be1, b2, g2, be2, b3, g3, be3, outf);
}

// Round 9
// 948.577 us; speedup vs baseline: 1.9668x; 1.0008x over previous
//
#include <hip/hip_runtime.h>
#include <math.h>

#define NPTS 4096
#define MC   1024
#define KNB  32

typedef __attribute__((ext_vector_type(8))) short bf16x8;
typedef __attribute__((ext_vector_type(4))) float f32x4;
typedef __attribute__((ext_vector_type(2))) float f32x2;

__device__ __forceinline__ unsigned short f2bf(float f) {
  unsigned int u = __float_as_uint(f);
  u = u + 0x7fffu + ((u >> 16) & 1u);   // round-to-nearest-even
  return (unsigned short)(u >> 16);
}

template <int CTRL>
__device__ __forceinline__ float dpp_max(float v) {
  int o = __builtin_amdgcn_update_dpp(__float_as_int(v), __float_as_int(v), CTRL, 0xF, 0xF, false);
  return fmaxf(v, __int_as_float(o));
}

// ---------------------------------------------------------------------------
// Kernel 1 (fused): blocks 0..15 = FPS, 16..1039 = feature transpose,
// 1040..1048 = weight pack. == R6 VERBATIM (banked: fused_pre ~673us,
// VGPR=88 resident; reproduced twice) == DO NOT TOUCH.
//
// SESSION LEDGER (counter-verified; do NOT revisit):
//   R1 8-wave single batch -> lockstep barrier (+138us); R2 volatile spin ->
//   serialized LDS (+640us); R3/R4/R5/R7 batch-pair & mux payload -> spill
//   (VGPR 116/64/44/48); R6 packed f32x2 update -> WIN 702->670us.
//   FPS remaining ~1330cyc/iter = dependent DPP->readlane->ballot->scan->
//   LDS->barrier->LDS->LDS chain at 1 wave/SIMD: latency floor.
//   R9: tail attack — mlp __threadfence_block (vmcnt(0) drains) removed.
// ---------------------------------------------------------------------------
struct FpsShared {
  float sx[NPTS], sy[NPTS], sz[NPTS];
  unsigned long long skey[2][4];
  float slog[3][MC];
};
struct TransShared {
  float tile[64][65];
};

__global__ __launch_bounds__(256, 1) void fused_pre(
    const float* __restrict__ points, const float* __restrict__ feats,
    const float* __restrict__ w1, const float* __restrict__ w2,
    const float* __restrict__ w3,
    unsigned short* __restrict__ featsT, unsigned short* __restrict__ wpack,
    float* __restrict__ out_cent) {
  __shared__ union { FpsShared f; TransShared tr; } S;
  const int blk = blockIdx.x;
  const int t = threadIdx.x;

  if (blk < 16) {
    // ======================= FPS =======================
    const int b = blk;
    const int w = t >> 6;
    const float* pb = points + (size_t)b * 3 * NPTS;

    // lane-owned idx for (k,c) = k*1024 + 4*t + c ; packed pair p=k*2+(c>>1),
    // element c&1 holds scalar point (k,c).
    f32x2 fx[8], fy[8], fz[8], dist[8];
#pragma unroll
    for (int k = 0; k < 4; ++k) {
      float4 X = ((const float4*)pb)[k * 256 + t];
      float4 Y = ((const float4*)(pb + NPTS))[k * 256 + t];
      float4 Z = ((const float4*)(pb + 2 * NPTS))[k * 256 + t];
      ((float4*)S.f.sx)[k * 256 + t] = X;
      ((float4*)S.f.sy)[k * 256 + t] = Y;
      ((float4*)S.f.sz)[k * 256 + t] = Z;
      fx[k * 2 + 0] = (f32x2){X.x, X.y}; fx[k * 2 + 1] = (f32x2){X.z, X.w};
      fy[k * 2 + 0] = (f32x2){Y.x, Y.y}; fy[k * 2 + 1] = (f32x2){Y.z, Y.w};
      fz[k * 2 + 0] = (f32x2){Z.x, Z.y}; fz[k * 2 + 1] = (f32x2){Z.z, Z.w};
    }
#pragma unroll
    for (int p = 0; p < 8; ++p) dist[p] = (f32x2){1e10f, 1e10f};
    __syncthreads();

    float lx = S.f.sx[0], ly = S.f.sy[0], lz = S.f.sz[0];

    for (int i = 0; i < MC; ++i) {
      if (t == 0) { S.f.slog[0][i] = lx; S.f.slog[1][i] = ly; S.f.slog[2][i] = lz; }
      if (i == MC - 1) break;

      // ---- packed distance update (bit-exact: contract off, elementwise
      //      IEEE rn == scalar __f*_rn chain) + per-lane max ----
      float m0, m1;
      {
#pragma clang fp contract(off)
        const f32x2 Lx = {lx, lx};
        const f32x2 Ly = {ly, ly};
        const f32x2 Lz = {lz, lz};
        m0 = -1.0f; m1 = -1.0f;
#pragma unroll
        for (int p = 0; p < 8; ++p) {
          f32x2 dx = fx[p] - Lx;
          f32x2 dy = fy[p] - Ly;
          f32x2 dz = fz[p] - Lz;
          f32x2 d  = dx * dx + dy * dy + dz * dz;   // pk_mul + pk_add, no fma
          float dm0 = fminf(dist[p][0], d[0]);
          float dm1 = fminf(dist[p][1], d[1]);
          dist[p][0] = dm0;
          dist[p][1] = dm1;
          m0 = fmaxf(m0, dm0);
          m1 = fmaxf(m1, dm1);
        }
      }
      float m = fmaxf(m0, m1);

      // ---- value-only wave64 max via DPP (result in lane 63) ----
      m = dpp_max<0x111>(m);   // row_shr:1
      m = dpp_max<0x112>(m);   // row_shr:2
      m = dpp_max<0x114>(m);   // row_shr:4
      m = dpp_max<0x118>(m);   // row_shr:8
      m = dpp_max<0x142>(m);   // row_bcast:15
      m = dpp_max<0x143>(m);   // row_bcast:31
      const float wv = __int_as_float(__builtin_amdgcn_readlane(__float_as_int(m), 63));

      // ---- recover lowest matching index: 16 ballots + SALU scan ----
      // global idx = k*1024 + 4*(w*64+lane) + c: scan k asc, then lowest
      // lane (ctz), then lowest c — exact lowest-index tie-break.
      unsigned long long mk[4][4];
#pragma unroll
      for (int k = 0; k < 4; ++k) {
        mk[k][0] = __ballot(dist[k * 2 + 0][0] == wv);
        mk[k][1] = __ballot(dist[k * 2 + 0][1] == wv);
        mk[k][2] = __ballot(dist[k * 2 + 1][0] == wv);
        mk[k][3] = __ballot(dist[k * 2 + 1][1] == wv);
      }
      unsigned long long s0 = 0, s1 = 0, s2 = 0, s3 = 0, anyk = 0;
      int sk = -1;
#pragma unroll
      for (int k = 0; k < 4; ++k) {
        unsigned long long a = mk[k][0] | mk[k][1] | mk[k][2] | mk[k][3];
        if (sk < 0 && a != 0ull) {
          sk = k; anyk = a;
          s0 = mk[k][0]; s1 = mk[k][1]; s2 = mk[k][2]; s3 = mk[k][3];
        }
      }
      const int l = __builtin_ctzll(anyk);
      const unsigned long long bit = 1ull << l;
      const int c = (s0 & bit) ? 0 : (s1 & bit) ? 1 : (s2 & bit) ? 2 : 3;
      const int selIdx = sk * 1024 + 256 * w + 4 * l + c;

      const int nb = i & 1;
      if ((t & 63) == 0)
        S.f.skey[nb][w] = ((unsigned long long)__float_as_uint(wv) << 32) | (unsigned int)~selIdx;
      __syncthreads();

      // ---- all lanes: max of 4 keys, then LDS broadcast of winner coords ----
      unsigned long long k0 = S.f.skey[nb][0], k1 = S.f.skey[nb][1];
      unsigned long long k2 = S.f.skey[nb][2], k3 = S.f.skey[nb][3];
      unsigned long long ka = (k0 > k1) ? k0 : k1;
      unsigned long long kb = (k2 > k3) ? k2 : k3;
      unsigned long long km = (ka > kb) ? ka : kb;
      const int sel = (int)(~(unsigned int)km);
      lx = S.f.sx[sel]; ly = S.f.sy[sel]; lz = S.f.sz[sel];
    }
    __syncthreads();
    // coalesced centroid output [3][1024] per batch
    float* oc = out_cent + (size_t)b * 3 * MC;
#pragma unroll
    for (int k = 0; k < 12; ++k) {
      int idx = t + k * 256;
      oc[idx] = ((const float*)S.f.slog)[idx];
    }
  } else if (blk < 16 + 1024) {
    // ================== feature transpose ==================
    const int rel = blk - 16;
    const int b = rel >> 6;
    const int n0 = (rel & 63) * 64;
    const float* src = feats + (size_t)b * 64 * NPTS;
    {
      const int n = t & 63, cbase = t >> 6;
#pragma unroll
      for (int j = 0; j < 16; ++j) {
        int cc = cbase + j * 4;
        S.tr.tile[cc][n] = src[(size_t)cc * NPTS + n0 + n];
      }
    }
    __syncthreads();
    {
      const int cc = t & 63, nbase = t >> 6;
      unsigned short* dst = featsT + ((size_t)b * NPTS + n0) * 64;
#pragma unroll
      for (int j = 0; j < 16; ++j) {
        int n = nbase + j * 4;
        dst[(size_t)n * 64 + cc] = f2bf(S.tr.tile[cc][n]);
      }
    }
  } else {
    // ================== weight pack (f = 0..35) ==================
    const int f = (blk - (16 + 1024)) * 4 + (t >> 6);
    const int lane = t & 63;
    if (f < 36) {
      int layer, kt, nt;
      if (f < 12)      { layer = 0; kt = f >> 2;        nt = f & 3; }
      else if (f < 20) { layer = 1; kt = (f - 12) >> 2; nt = (f - 12) & 3; }
      else             { layer = 2; kt = (f - 20) >> 3; nt = (f - 20) & 7; }
      const int o = nt * 16 + (lane & 15);
      unsigned short* dst = wpack + ((size_t)f * 64 + lane) * 8;
#pragma unroll
      for (int j = 0; j < 8; ++j) {
        int k = kt * 32 + (lane >> 4) * 8 + j;
        float x = 0.0f;
        if (layer == 0)      { if (k < 67) { int cin = (k < 64) ? (k + 3) : (k - 64); x = w1[o * 67 + cin]; } }
        else if (layer == 1) { x = w2[o * 64 + k]; }
        else                 { x = w3[o * 64 + k]; }
        dst[j] = f2bf(x);
      }
    }
  }
}

// ---------------------------------------------------------------------------
// Kernel 2: ball query. Centroids read from out_cent layout [B,3,MC].
// ---------------------------------------------------------------------------
__global__ __launch_bounds__(256) void ball_query_kernel(const float* __restrict__ points,
                                                         const float* __restrict__ cent,
                                                         int* __restrict__ nidx) {
  __shared__ float sx[NPTS], sy[NPTS], sz[NPTS];
  __shared__ int lists[4][KNB];
  const int b  = blockIdx.x >> 4;
  const int cb = blockIdx.x & 15;
  const int t = threadIdx.x;
  const float* pb = points + (size_t)b * 3 * NPTS;
#pragma unroll
  for (int j = 0; j < 4; ++j) {
    int i4 = t + j * 256;
    ((float4*)sx)[i4] = ((const float4*)pb)[i4];
    ((float4*)sy)[i4] = ((const float4*)(pb + NPTS))[i4];
    ((float4*)sz)[i4] = ((const float4*)(pb + 2 * NPTS))[i4];
  }
  __syncthreads();
  const int w = t >> 6, lane = t & 63;
  const float R2 = (float)(0.2 * 0.2);
  const float* cbp = cent + (size_t)b * 3 * MC;
  for (int cm = 0; cm < 16; ++cm) {
    const int m  = cb * 64 + w * 16 + cm;
    const int bm = b * MC + m;
    const float cx = cbp[m], cy = cbp[MC + m], cz = cbp[2 * MC + m];
    const float c2 = __fadd_rn(__fadd_rn(__fmul_rn(cx, cx), __fmul_rn(cy, cy)), __fmul_rn(cz, cz));
    int cnt = 0;
    for (int ch = 0; ch < 64; ++ch) {
      const int n = ch * 64 + lane;
      float x = sx[n], y = sy[n], z = sz[n];
      float p2  = __fadd_rn(__fadd_rn(__fmul_rn(x, x),  __fmul_rn(y, y)),  __fmul_rn(z, z));
      float dot = __fadd_rn(__fadd_rn(__fmul_rn(cx, x), __fmul_rn(cy, y)), __fmul_rn(cz, z));
      float d2  = __fsub_rn(__fadd_rn(c2, p2), __fmul_rn(2.0f, dot));
      bool hit = (d2 <= R2);
      unsigned long long msk = __ballot(hit);
      if (hit) {
        int pos = cnt + __popcll(msk & ((1ull << lane) - 1ull));
        if (pos < KNB) lists[w][pos] = n;
      }
      cnt += __popcll(msk);
      if (cnt >= KNB) break;
    }
    if (lane < KNB) {
      int first = lists[w][0];
      int v = (lane < cnt) ? lists[w][lane] : first;
      nidx[(size_t)bm * KNB + lane] = v;
    }
  }
}

// ---------------------------------------------------------------------------
// Kernel 3: fused gather + 3-layer MLP (bf16 MFMA 16x16x32) + maxpool.
// R9: removed the 3x per-iteration __threadfence_block (each compiled to a
// full s_waitcnt vmcnt(0) drain, serializing featsT gathers against every
// layer boundary). They were only ordering each wave's OWN Hs[w] LDS
// writes vs reads — per-wave DS ops execute in order and the compiler
// inserts the lgkmcnt waits for dependent reads, so no fence is needed.
// The one true cross-wave handoff (obuf -> final store) keeps its
// __syncthreads. Added #pragma unroll 2 on the independent `it` loop so
// the scheduler can hoist iteration it+1's nidx/featsT gathers above
// iteration it's MFMA work (gathers no longer drained by fences).
// ---------------------------------------------------------------------------
__global__ __launch_bounds__(256) void mlp_kernel(
    const float* __restrict__ points,
    const float* __restrict__ cent,
    const int* __restrict__ nidx,
    const unsigned short* __restrict__ featsT,
    const unsigned short* __restrict__ wpack,
    const float* __restrict__ b1, const float* __restrict__ g1, const float* __restrict__ be1,
    const float* __restrict__ b2, const float* __restrict__ g2, const float* __restrict__ be2,
    const float* __restrict__ b3, const float* __restrict__ g3, const float* __restrict__ be3,
    float* __restrict__ out) {
  __shared__ __align__(16) unsigned short Hs[4][2][32 * 72];
  __shared__ __align__(16) float obuf[128 * 20];
  const int t = threadIdx.x;
  const int w = t >> 6, lane = t & 63;
  const int r = lane & 15, q = lane >> 4;
  const float inv_s = 1.0f / sqrtf(1.0f + 1e-5f);

  float pb1[4], ps1[4], pe1[4], pb2[4], ps2[4], pe2[4], pb3[8], ps3[8], pe3[8];
#pragma unroll
  for (int nt = 0; nt < 4; ++nt) {
    int o = nt * 16 + r;
    pb1[nt] = b1[o]; ps1[nt] = g1[o] * inv_s; pe1[nt] = be1[o];
    pb2[nt] = b2[o]; ps2[nt] = g2[o] * inv_s; pe2[nt] = be2[o];
  }
#pragma unroll
  for (int nt = 0; nt < 8; ++nt) {
    int o = nt * 16 + r;
    pb3[nt] = b3[o]; ps3[nt] = g3[o] * inv_s; pe3[nt] = be3[o];
  }
  const int bm0 = blockIdx.x * 16;
  const int b   = bm0 >> 10;
  const int m0  = bm0 & 1023;
  const float* ptsb = points + (size_t)b * 3 * NPTS;
  const float* cbp  = cent + (size_t)b * 3 * MC;

#pragma unroll 2
  for (int it = 0; it < 4; ++it) {
    const int ml = it * 4 + w;
    const int bm = bm0 + ml;
    const int m  = bm & 1023;
    const int n0 = nidx[(size_t)bm * KNB + r];
    const int n1 = nidx[(size_t)bm * KNB + 16 + r];
    const float cx = cbp[m], cy = cbp[MC + m], cz = cbp[2 * MC + m];

    // ---- layer 1 ----
    bf16x8 aF[2][2];
#pragma unroll
    for (int mt = 0; mt < 2; ++mt) {
      int n = mt ? n1 : n0;
      const unsigned short* rowp = featsT + ((size_t)b * NPTS + n) * 64 + q * 8;
      aF[mt][0] = *(const bf16x8*)(rowp);
      aF[mt][1] = *(const bf16x8*)(rowp + 32);
    }
    bf16x8 aL[2];
#pragma unroll
    for (int mt = 0; mt < 2; ++mt) {
      bf16x8 a = {0, 0, 0, 0, 0, 0, 0, 0};
      if (q == 0) {
        int n = mt ? n1 : n0;
        a[0] = (short)f2bf(ptsb[n] - cx);
        a[1] = (short)f2bf(ptsb[NPTS + n] - cy);
        a[2] = (short)f2bf(ptsb[2 * NPTS + n] - cz);
      }
      aL[mt] = a;
    }
    f32x4 acc1[2][4];
#pragma unroll
    for (int mt = 0; mt < 2; ++mt)
#pragma unroll
      for (int nt = 0; nt < 4; ++nt) acc1[mt][nt] = (f32x4){0.f, 0.f, 0.f, 0.f};
#pragma unroll
    for (int kt = 0; kt < 3; ++kt) {
#pragma unroll
      for (int nt = 0; nt < 4; ++nt) {
        bf16x8 wf = *(const bf16x8*)(wpack + ((size_t)(kt * 4 + nt) * 64 + lane) * 8);
#pragma unroll
        for (int mt = 0; mt < 2; ++mt) {
          bf16x8 a = (kt < 2) ? aF[mt][kt] : aL[mt];
          acc1[mt][nt] = __builtin_amdgcn_mfma_f32_16x16x32_bf16(a, wf, acc1[mt][nt], 0, 0, 0);
        }
      }
    }
#pragma unroll
    for (int mt = 0; mt < 2; ++mt)
#pragma unroll
      for (int nt = 0; nt < 4; ++nt)
#pragma unroll
        for (int rr = 0; rr < 4; ++rr) {
          float y = (acc1[mt][nt][rr] + pb1[nt]) * ps1[nt] + pe1[nt];
          y = fmaxf(y, 0.0f);
          Hs[w][0][(mt * 16 + q * 4 + rr) * 72 + nt * 16 + r] = f2bf(y);
        }

    // ---- layer 2 ----
    f32x4 acc2[2][4];
#pragma unroll
    for (int mt = 0; mt < 2; ++mt)
#pragma unroll
      for (int nt = 0; nt < 4; ++nt) acc2[mt][nt] = (f32x4){0.f, 0.f, 0.f, 0.f};
#pragma unroll
    for (int kt = 0; kt < 2; ++kt) {
      bf16x8 a0 = *(const bf16x8*)&Hs[w][0][(0 * 16 + r) * 72 + kt * 32 + q * 8];
      bf16x8 a1 = *(const bf16x8*)&Hs[w][0][(1 * 16 + r) * 72 + kt * 32 + q * 8];
#pragma unroll
      for (int nt = 0; nt < 4; ++nt) {
        bf16x8 wf = *(const bf16x8*)(wpack + ((size_t)(12 + kt * 4 + nt) * 64 + lane) * 8);
        acc2[0][nt] = __builtin_amdgcn_mfma_f32_16x16x32_bf16(a0, wf, acc2[0][nt], 0, 0, 0);
        acc2[1][nt] = __builtin_amdgcn_mfma_f32_16x16x32_bf16(a1, wf, acc2[1][nt], 0, 0, 0);
      }
    }
#pragma unroll
    for (int mt = 0; mt < 2; ++mt)
#pragma unroll
      for (int nt = 0; nt < 4; ++nt)
#pragma unroll
        for (int rr = 0; rr < 4; ++rr) {
          float y = (acc2[mt][nt][rr] + pb2[nt]) * ps2[nt] + pe2[nt];
          y = fmaxf(y, 0.0f);
          Hs[w][1][(mt * 16 + q * 4 + rr) * 72 + nt * 16 + r] = f2bf(y);
        }

    // ---- layer 3 + maxpool ----
    f32x4 acc3[2][8];
#pragma unroll
    for (int mt = 0; mt < 2; ++mt)
#pragma unroll
      for (int nt = 0; nt < 8; ++nt) acc3[mt][nt] = (f32x4){0.f, 0.f, 0.f, 0.f};
#pragma unroll
    for (int kt = 0; kt < 2; ++kt) {
      bf16x8 a0 = *(const bf16x8*)&Hs[w][1][(0 * 16 + r) * 72 + kt * 32 + q * 8];
      bf16x8 a1 = *(const bf16x8*)&Hs[w][1][(1 * 16 + r) * 72 + kt * 32 + q * 8];
#pragma unroll
      for (int nt = 0; nt < 8; ++nt) {
        bf16x8 wf = *(const bf16x8*)(wpack + ((size_t)(20 + kt * 8 + nt) * 64 + lane) * 8);
        acc3[0][nt] = __builtin_amdgcn_mfma_f32_16x16x32_bf16(a0, wf, acc3[0][nt], 0, 0, 0);
        acc3[1][nt] = __builtin_amdgcn_mfma_f32_16x16x32_bf16(a1, wf, acc3[1][nt], 0, 0, 0);
      }
    }
#pragma unroll
    for (int nt = 0; nt < 8; ++nt) {
      float pm = 0.0f;   // relu outputs are >= 0
#pragma unroll
      for (int mt = 0; mt < 2; ++mt)
#pragma unroll
        for (int rr = 0; rr < 4; ++rr) {
          float y = (acc3[mt][nt][rr] + pb3[nt]) * ps3[nt] + pe3[nt];
          y = fmaxf(y, 0.0f);
          pm = fmaxf(pm, y);
        }
      pm = fmaxf(pm, __shfl_xor(pm, 16));
      pm = fmaxf(pm, __shfl_xor(pm, 32));
      if (q == 0) obuf[(nt * 16 + r) * 20 + ml] = pm;
    }
  }
  __syncthreads();
  // coalesced-ish store: thread t -> channel t>>1, half (t&1)*8
  {
    const int ch = t >> 1, mh = (t & 1) * 8;
    float4 u0 = *(const float4*)&obuf[ch * 20 + mh];
    float4 u1 = *(const float4*)&obuf[ch * 20 + mh + 4];
    float* outp = out + ((size_t)b * 128 + ch) * 1024 + m0 + mh;
    *(float4*)(outp)     = u0;
    *(float4*)(outp + 4) = u1;
  }
}

// ---------------------------------------------------------------------------
extern "C" void kernel_launch(void* const* d_in, const int* in_sizes, int n_in,
                              void* d_out, int out_size, void* d_ws, size_t ws_size,
                              hipStream_t stream) {
  (void)in_sizes; (void)n_in; (void)out_size; (void)ws_size;
  const float* points   = (const float*)d_in[0];
  const float* features = (const float*)d_in[1];
  const float* w1  = (const float*)d_in[2];
  const float* b1  = (const float*)d_in[3];
  const float* g1  = (const float*)d_in[4];
  const float* be1 = (const float*)d_in[5];
  const float* w2  = (const float*)d_in[6];
  const float* b2  = (const float*)d_in[7];
  const float* g2  = (const float*)d_in[8];
  const float* be2 = (const float*)d_in[9];
  const float* w3  = (const float*)d_in[10];
  const float* b3  = (const float*)d_in[11];
  const float* g3  = (const float*)d_in[12];
  const float* be3 = (const float*)d_in[13];

  float* outc = (float*)d_out;                  // centroids [16,3,1024]
  float* outf = outc + 16 * 3 * 1024;           // features  [16,128,1024]

  char* ws = (char*)d_ws;
  int*            nidx    = (int*)(ws);                      // 16384*32*4  = 2 MiB
  unsigned short* featsT  = (unsigned short*)(ws + 0x200000);// 16*4096*64*2= 8 MiB
  unsigned short* wpack   = (unsigned short*)(ws + 0xA00000);// 36*1024 B

  fused_pre<<<16 + 1024 + 9, 256, 0, stream>>>(points, features, w1, w2, w3,
                                               featsT, wpack, outc);
  ball_query_kernel<<<256, 256, 0, stream>>>(points, outc, nidx);
  mlp_kernel<<<1024, 256, 0, stream>>>(points, outc, nidx, featsT, wpack,
                                       b1, g1, be1, b2, g2, be2, b3, g3, be3, outf);
}